// Round 5
// baseline (143.619 us; speedup 1.0000x reference)
//
#include <hip/hip_runtime.h>
#include <hip/hip_bf16.h>
#include <cstdint>

using u16 = unsigned short;
typedef short bf16x8 __attribute__((ext_vector_type(8)));
typedef float f32x4 __attribute__((ext_vector_type(4)));
typedef float f32x16 __attribute__((ext_vector_type(16)));
typedef u16 u16x4 __attribute__((ext_vector_type(4)));
typedef u16 u16x8 __attribute__((ext_vector_type(8)));

// ---------- helpers ----------
__device__ __forceinline__ u16 f2bf(float f) {
  union { float f; uint32_t u; } v; v.f = f;
  uint32_t r = (v.u + 0x7fffu + ((v.u >> 16) & 1u)) >> 16;  // RNE
  return (u16)r;
}

__device__ __forceinline__ float bf2f(u16 u) {
  union { uint32_t u; float f; } v; v.u = (uint32_t)u << 16; return v.f;
}

__device__ __forceinline__ void async16(const void* g, void* l) {
  __builtin_amdgcn_global_load_lds(
      (const __attribute__((address_space(1))) uint32_t*)g,
      (__attribute__((address_space(3))) uint32_t*)l, 16, 0, 0);
}

__device__ __forceinline__ uint32_t cvtpk(float a, float b) {
  uint32_t r;
  asm("v_cvt_pk_bf16_f32 %0, %1, %2" : "=v"(r) : "v"(a), "v"(b));
  return r;
}

// swap upper 32 lanes of a with lower 32 lanes of b
__device__ __forceinline__ void plswap(uint32_t& a, uint32_t& b) {
  asm volatile("v_permlane32_swap_b32 %0, %1" : "+v"(a), "+v"(b));
}

// ---------- fused prep: cvt x (blocks 0..4095) + 4x weight transpose (4096..5119) ----------
__global__ __launch_bounds__(256) void prep_kernel(
    const float* __restrict__ x, const float* __restrict__ wq, const float* __restrict__ wk,
    const float* __restrict__ wv, const float* __restrict__ wo,
    u16* __restrict__ xb, u16* __restrict__ Wqt, u16* __restrict__ Wkt,
    u16* __restrict__ Wvt, u16* __restrict__ Wot) {
  __shared__ float tile[64][65];
  const int tid = threadIdx.x;
  const int bid = blockIdx.x;
  if (bid < 4096) {
    int i = (bid * 256 + tid) * 4;
    float4 v = *(const float4*)(x + i);
    u16x4 o;
    o[0] = f2bf(v.x); o[1] = f2bf(v.y); o[2] = f2bf(v.z); o[3] = f2bf(v.w);
    *(u16x4*)(xb + i) = o;
    return;
  }
  const int id = bid - 4096;
  const int wsel = id >> 8, sub = id & 255;
  const float* W = (wsel == 0) ? wq : (wsel == 1) ? wk : (wsel == 2) ? wv : wo;
  u16* Wt = (wsel == 0) ? Wqt : (wsel == 1) ? Wkt : (wsel == 2) ? Wvt : Wot;
  const int k0 = (sub & 15) * 64, n0 = (sub >> 4) * 64;
#pragma unroll
  for (int i = 0; i < 4; ++i) {
    int c = i * 256 + tid;
    int r = c >> 4, c4 = c & 15;
    float4 v = *(const float4*)(W + (size_t)(k0 + r) * 1024 + n0 + c4 * 4);
    tile[r][c4 * 4 + 0] = v.x; tile[r][c4 * 4 + 1] = v.y;
    tile[r][c4 * 4 + 2] = v.z; tile[r][c4 * 4 + 3] = v.w;
  }
  __syncthreads();
#pragma unroll
  for (int i = 0; i < 2; ++i) {
    int c = i * 256 + tid;
    int n = c >> 3, kc = c & 7;
    u16x8 o;
#pragma unroll
    for (int j = 0; j < 8; ++j) o[j] = f2bf(tile[kc * 8 + j][n]);
    *(u16x8*)(Wt + (size_t)(n0 + n) * 1024 + k0 + kc * 8) = o;
  }
}

// ---------- shared GEMM mainloop: C(128x128) = A(128xK) * Bt(128xK)^T, K=1024 ----------
__device__ __forceinline__ void stage_ab(const u16* A, const u16* Bt, int m0, int n0, int kt,
                                         u16* As, u16* Bs, int w, int lane) {
#pragma unroll
  for (int c = 0; c < 2; ++c) {
    int chunk = w * 128 + c * 64 + lane;
    int row = chunk >> 2, cc = chunk & 3;
    int koff = kt * 32 + ((cc ^ (row & 3)) << 3);
    const u16* ga = A + (size_t)(m0 + row) * 1024 + koff;
    async16(ga, As + (size_t)(w * 128 + c * 64) * 8);
    const u16* gb = Bt + (size_t)(n0 + row) * 1024 + koff;
    async16(gb, Bs + (size_t)(w * 128 + c * 64) * 8);
  }
}

__device__ __forceinline__ void gemm_mainloop(const u16* A, const u16* Bt, int m0, int n0,
                                              u16 (*As)[4096], u16 (*Bs)[4096], f32x4 acc[4][4]) {
  const int tid = threadIdx.x, w = tid >> 6, lane = tid & 63, lo = lane & 15, hi = lane >> 4;
  const int mb = (w >> 1) * 64, nb = (w & 1) * 64;
  stage_ab(A, Bt, m0, n0, 0, As[0], Bs[0], w, lane);
  __syncthreads();
  for (int kt = 0; kt < 32; ++kt) {
    int cur = kt & 1;
    if (kt + 1 < 32) stage_ab(A, Bt, m0, n0, kt + 1, As[cur ^ 1], Bs[cur ^ 1], w, lane);
    bf16x8 af[4], bfr[4];
#pragma unroll
    for (int i = 0; i < 4; ++i) {
      int ra = mb + i * 16 + lo;
      af[i] = *(const bf16x8*)(As[cur] + ra * 32 + ((hi ^ (ra & 3)) << 3));
      int rb = nb + i * 16 + lo;
      bfr[i] = *(const bf16x8*)(Bs[cur] + rb * 32 + ((hi ^ (rb & 3)) << 3));
    }
#pragma unroll
    for (int i = 0; i < 4; ++i)
#pragma unroll
      for (int j = 0; j < 4; ++j)
        acc[i][j] = __builtin_amdgcn_mfma_f32_16x16x32_bf16(af[i], bfr[j], acc[i][j], 0, 0, 0);
    __syncthreads();
  }
}

// ---------- QKV projection + RoPE + scatter ----------
__global__ __launch_bounds__(256) void qkv_gemm_kernel(
    const u16* __restrict__ xb, const u16* __restrict__ Wqt, const u16* __restrict__ Wkt,
    const u16* __restrict__ Wvt, u16* __restrict__ Qh, u16* __restrict__ Kh, u16* __restrict__ Vt) {
  __shared__ u16 As[2][4096];
  __shared__ u16 Bs[2][4096];
  const int mode = blockIdx.z;
  const u16* Bt = (mode == 0) ? Wqt : (mode == 1) ? Wkt : Wvt;
  const int m0 = blockIdx.x * 128, n0 = blockIdx.y * 128;
  f32x4 acc[4][4];
  const f32x4 z4 = {0.f, 0.f, 0.f, 0.f};
#pragma unroll
  for (int i = 0; i < 4; ++i)
#pragma unroll
    for (int j = 0; j < 4; ++j) acc[i][j] = z4;
  gemm_mainloop(xb, Bt, m0, n0, As, Bs, acc);

  const int tid = threadIdx.x, w = tid >> 6, lane = tid & 63, lo = lane & 15, hi = lane >> 4;
  const int h = blockIdx.y * 2 + (w & 1);
  const int mrow0 = m0 + (w >> 1) * 64;
  if (mode < 2) {
    u16* Out = (mode == 0) ? Qh : Kh;
    // Q pre-scaled by 1/sqrt(64) * log2(e): attention scores land in exp2 domain
    const float qscale = (mode == 0) ? 0.18033688011112042f : 1.0f;
    const float invf0 = exp2f(-(float)lo * 0.41524101186092034f);
    const float invf1 = invf0 * 0.01f;
#pragma unroll
    for (int mi = 0; mi < 4; ++mi) {
#pragma unroll
      for (int r = 0; r < 4; ++r) {
        int tg = mrow0 + mi * 16 + hi * 4 + r;
        int b = tg >> 11, tp = tg & 2047;
        float c0, s0, c1, s1;
        __sincosf((float)tp * invf0, &s0, &c0);
        __sincosf((float)tp * invf1, &s1, &c1);
        size_t obase = ((size_t)(b * 16 + h) * 2048 + tp) * 64 + lo;
#pragma unroll
        for (int nf = 0; nf < 4; ++nf) {
          float v = acc[mi][nf][r];
          float rot = (nf < 2) ? -acc[mi][nf + 2][r] : acc[mi][nf - 2][r];
          float cs = (nf & 1) ? c1 : c0;
          float sn = (nf & 1) ? s1 : s0;
          Out[obase + nf * 16] = f2bf((v * cs + rot * sn) * qscale);
        }
      }
    }
  } else {
#pragma unroll
    for (int mi = 0; mi < 4; ++mi) {
      int tg0 = mrow0 + mi * 16 + hi * 4;
      int b = tg0 >> 11, tp0 = tg0 & 2047;
#pragma unroll
      for (int nf = 0; nf < 4; ++nf) {
        int d = nf * 16 + lo;
        u16x4 pk;
#pragma unroll
        for (int r = 0; r < 4; ++r) pk[r] = f2bf(acc[mi][nf][r]);
        *(u16x4*)(Vt + ((size_t)(b * 16 + h) * 64 + d) * 2048 + tp0) = pk;
      }
    }
  }
}

// ---------- flash attention: 8 waves = 2 q-subgroups x 4 key-quarters, KVBLK=128 ----------
// block = (qtp, bh), 512 thr. q-tiles 64 rows paired (qtp, 31-qtp) => exactly 17
// 128-key tile iterations/block. Wave (sg, p): q rows q0+32*sg+lane&31, keys
// [32p, 32p+32) of each tile. Swapped-operand 32x32 MFMA, in-register softmax.
// 4-way key partials merged per q-tile through the freed LDS double-buffer (bf16).
__global__ __launch_bounds__(512) void attn_kernel(const u16* __restrict__ Qh, const u16* __restrict__ Kh,
                                                   const u16* __restrict__ Vt, u16* __restrict__ ctx) {
  __shared__ u16 pool[2][16384];  // [buf]: K 128x64 at 0..8191 (chunk^=key&7), V 64x128 at 8192.. (chunk^=d&7, 16 chunks/row)
  __shared__ float Msm[2][3][32];
  __shared__ float Lsm[2][3][32];
  const int qtp = blockIdx.x, bh = blockIdx.y;
  const int tid = threadIdx.x, w = tid >> 6, lane = tid & 63;
  const int sg = w >> 2, p = w & 3;
  const int lo5 = lane & 31, hi = lane >> 5;
  const size_t kbh = (size_t)bh * 2048 * 64;
  const size_t vbh = (size_t)bh * 64 * 2048;
  const int bb = bh >> 4, h = bh & 15;

  for (int half = 0; half < 2; ++half) {
    const int qt = half ? (31 - qtp) : qtp;
    const int q0 = qt * 64;
    const int nit = (qt + 2) >> 1;  // number of 128-key tiles (even qt: last tile half-masked)
    const int tq = q0 + 32 * sg + lo5;

    // Q fragments (B-operand): q = col = lo5, k-elems = 16*d + 8*hi + j
    const u16* Qrow = Qh + ((size_t)bh * 2048 + tq) * 64;
    bf16x8 qf[4];
#pragma unroll
    for (int d = 0; d < 4; ++d) qf[d] = *(const bf16x8*)(Qrow + 16 * d + 8 * hi);

    f32x16 O0, O1;
#pragma unroll
    for (int r = 0; r < 16; ++r) { O0[r] = 0.f; O1[r] = 0.f; }
    float m_run = -1e30f, l_run = 0.f;

    __syncthreads();  // previous half done with LDS (incl. merge reads)
    // stage tile 0 into buf 0: 512 threads x 2 chunks each for K and V
#pragma unroll
    for (int c = 0; c < 2; ++c) {
      int ck = c * 512 + tid;            // K chunk 0..1023
      int key = ck >> 3, cc = ck & 7;
      int koff = (cc ^ (key & 7)) << 3;
      async16(Kh + kbh + (size_t)key * 64 + koff, pool[0] + (size_t)ck * 8);
      int dv = ck >> 4, vc = ck & 15;    // V chunk 0..1023
      int kc = (vc & 8) | ((vc & 7) ^ (dv & 7));
      async16(Vt + vbh + (size_t)dv * 2048 + kc * 8, pool[0] + 8192 + (size_t)ck * 8);
    }

    for (int t = 0; t < nit; ++t) {
      const int cur = t & 1;
      __syncthreads();  // drains vmcnt: buf[cur] ready, buf[cur^1] free
      if (t + 1 < nit) {
        int kv0n = (t + 1) * 128;
#pragma unroll
        for (int c = 0; c < 2; ++c) {
          int ck = c * 512 + tid;
          int key = ck >> 3, cc = ck & 7;
          int koff = (cc ^ (key & 7)) << 3;
          async16(Kh + kbh + (size_t)(kv0n + key) * 64 + koff, pool[cur ^ 1] + (size_t)ck * 8);
          int dv = ck >> 4, vc = ck & 15;
          int kc = (vc & 8) | ((vc & 7) ^ (dv & 7));
          async16(Vt + vbh + (size_t)dv * 2048 + kv0n + kc * 8, pool[cur ^ 1] + 8192 + (size_t)ck * 8);
        }
      }

      // S[key][q] over this wave's 32-key quarter (K rows 32p..32p+31 of the tile)
      const u16* Ksc = pool[cur];
      const u16* Vsc = pool[cur] + 8192;
      f32x16 s;
#pragma unroll
      for (int r = 0; r < 16; ++r) s[r] = 0.f;
      __builtin_amdgcn_s_setprio(1);
#pragma unroll
      for (int d = 0; d < 4; ++d) {
        int sw = ((2 * d + hi) ^ (lo5 & 7)) << 3;  // (32p+lo5)&7 == lo5&7
        bf16x8 ka = *(const bf16x8*)(Ksc + (32 * p + lo5) * 64 + sw);
        s = __builtin_amdgcn_mfma_f32_32x32x16_bf16(ka, qf[d], s, 0, 0, 0);
      }
      __builtin_amdgcn_s_setprio(0);

      // causal mask (last tile only); lane's key r: 128t + (r&3)+8*(r>>2)+4hi+32p
      if (t == nit - 1) {
        int qrel = tq - 128 * t - 32 * p - 4 * hi;
#pragma unroll
        for (int r = 0; r < 16; ++r) {
          int kl = (r & 3) + 8 * (r >> 2);
          if (kl > qrel) s[r] = -1e30f;
        }
      }

      // in-register online softmax: lane owns q-row (16 keys; partner lane^32 has 16)
      float pm = -1e30f;
#pragma unroll
      for (int r = 0; r < 16; ++r) pm = fmaxf(pm, s[r]);
      pm = fmaxf(pm, __shfl_xor(pm, 32));
      float alpha = 1.f;
      if (!__all(pm <= m_run)) {
        float mnew = fmaxf(m_run, pm);
        alpha = exp2f(m_run - mnew);
        m_run = mnew;
#pragma unroll
        for (int r = 0; r < 16; ++r) { O0[r] *= alpha; O1[r] *= alpha; }
      }
      float ls = 0.f;
#pragma unroll
      for (int r = 0; r < 16; ++r) {
        float pr = exp2f(s[r] - m_run);
        s[r] = pr;
        ls += pr;
      }
      ls += __shfl_xor(ls, 32);
      l_run = l_run * alpha + ls;

      // pack P to bf16 words and build PV A-fragments via permlane swaps
      uint32_t W0[8];
#pragma unroll
      for (int i = 0; i < 8; ++i) W0[i] = cvtpk(s[2 * i], s[2 * i + 1]);

      __builtin_amdgcn_s_setprio(1);
#pragma unroll
      for (int ks = 0; ks < 2; ++ks) {
        uint32_t a = W0[4 * ks + 0], d2 = W0[4 * ks + 1], c2 = W0[4 * ks + 2], e2 = W0[4 * ks + 3];
        plswap(a, c2);
        plswap(d2, e2);
        union { uint32_t u[4]; bf16x8 v; } f;
        f.u[0] = a; f.u[1] = d2; f.u[2] = c2; f.u[3] = e2;
        int vch = 4 * p + 2 * ks + hi;  // key chunk (of 16) of this wave's quarter
        int swc = (vch & 8) | ((vch & 7) ^ (lo5 & 7));  // (32+lo5)&7 == lo5&7
        bf16x8 v0 = *(const bf16x8*)(Vsc + lo5 * 128 + swc * 8);
        bf16x8 v1 = *(const bf16x8*)(Vsc + (32 + lo5) * 128 + swc * 8);
        O0 = __builtin_amdgcn_mfma_f32_32x32x16_bf16(v0, f.v, O0, 0, 0, 0);
        O1 = __builtin_amdgcn_mfma_f32_32x32x16_bf16(v1, f.v, O1, 0, 0, 0);
      }
      __builtin_amdgcn_s_setprio(0);
    }

    // ---- merge 4 key-quarter partials through the freed buffer pool[o] ----
    const int o = nit & 1;  // buffer NOT used by the last compute iteration
    if (p != 0) {
      u16* om = pool[o] + (size_t)((sg * 3 + (p - 1)) * 32 + lo5) * 68;
#pragma unroll
      for (int g = 0; g < 4; ++g) {
        int off = 8 * g + 4 * hi;
        u16x4 w0, w1;
#pragma unroll
        for (int j = 0; j < 4; ++j) { w0[j] = f2bf(O0[4 * g + j]); w1[j] = f2bf(O1[4 * g + j]); }
        *(u16x4*)(om + off) = w0;
        *(u16x4*)(om + 32 + off) = w1;
      }
      if (hi == 0) { Msm[sg][p - 1][lo5] = m_run; Lsm[sg][p - 1][lo5] = l_run; }
    }
    __syncthreads();
    if (p == 0) {
      float m1 = Msm[sg][0][lo5], m2 = Msm[sg][1][lo5], m3 = Msm[sg][2][lo5];
      float l1 = Lsm[sg][0][lo5], l2 = Lsm[sg][1][lo5], l3 = Lsm[sg][2][lo5];
      float mm = fmaxf(fmaxf(m_run, m1), fmaxf(m2, m3));
      float a0 = exp2f(m_run - mm), a1 = exp2f(m1 - mm), a2 = exp2f(m2 - mm), a3 = exp2f(m3 - mm);
      float invl = 1.0f / (l_run * a0 + l1 * a1 + l2 * a2 + l3 * a3);
      const u16* om1 = pool[o] + (size_t)((sg * 3 + 0) * 32 + lo5) * 68;
      const u16* om2 = pool[o] + (size_t)((sg * 3 + 1) * 32 + lo5) * 68;
      const u16* om3 = pool[o] + (size_t)((sg * 3 + 2) * 32 + lo5) * 68;
      size_t rowb = ((size_t)(bb * 2048 + tq)) * 1024 + h * 64;
#pragma unroll
      for (int g = 0; g < 4; ++g) {
        int off = 8 * g + 4 * hi;
        u16x4 q1 = *(const u16x4*)(om1 + off), q2 = *(const u16x4*)(om2 + off), q3 = *(const u16x4*)(om3 + off);
        u16x4 pk;
#pragma unroll
        for (int j = 0; j < 4; ++j)
          pk[j] = f2bf((O0[4 * g + j] * a0 + bf2f(q1[j]) * a1 + bf2f(q2[j]) * a2 + bf2f(q3[j]) * a3) * invl);
        *(u16x4*)(ctx + rowb + off) = pk;
        u16x4 r1 = *(const u16x4*)(om1 + 32 + off), r2 = *(const u16x4*)(om2 + 32 + off), r3 = *(const u16x4*)(om3 + 32 + off);
#pragma unroll
        for (int j = 0; j < 4; ++j)
          pk[j] = f2bf((O1[4 * g + j] * a0 + bf2f(r1[j]) * a1 + bf2f(r2[j]) * a2 + bf2f(r3[j]) * a3) * invl);
        *(u16x4*)(ctx + rowb + 32 + off) = pk;
      }
    }
  }
}

// ---------- output projection: out = ctx @ w_o (f32 out) ----------
__global__ __launch_bounds__(256) void out_gemm_kernel(const u16* __restrict__ ctxb,
                                                       const u16* __restrict__ Wot,
                                                       float* __restrict__ out) {
  __shared__ u16 As[2][4096];
  __shared__ u16 Bs[2][4096];
  const int m0 = blockIdx.x * 128, n0 = blockIdx.y * 128;
  f32x4 acc[4][4];
  const f32x4 z4 = {0.f, 0.f, 0.f, 0.f};
#pragma unroll
  for (int i = 0; i < 4; ++i)
#pragma unroll
    for (int j = 0; j < 4; ++j) acc[i][j] = z4;
  gemm_mainloop(ctxb, Wot, m0, n0, As, Bs, acc);
  const int tid = threadIdx.x, w = tid >> 6, lane = tid & 63, lo = lane & 15, hi = lane >> 4;
  const int col0 = n0 + (w & 1) * 64 + lo;
#pragma unroll
  for (int mi = 0; mi < 4; ++mi)
#pragma unroll
    for (int r = 0; r < 4; ++r) {
      int tg = m0 + (w >> 1) * 64 + mi * 16 + hi * 4 + r;
#pragma unroll
      for (int nf = 0; nf < 4; ++nf)
        out[(size_t)tg * 1024 + col0 + nf * 16] = acc[mi][nf][r];
    }
}

// ---------- launch ----------
extern "C" void kernel_launch(void* const* d_in, const int* in_sizes, int n_in,
                              void* d_out, int out_size, void* d_ws, size_t ws_size,
                              hipStream_t stream) {
  (void)in_sizes; (void)n_in; (void)out_size; (void)ws_size;
  const float* x  = (const float*)d_in[0];
  const float* wq = (const float*)d_in[1];
  const float* wk = (const float*)d_in[2];
  const float* wv = (const float*)d_in[3];
  const float* wo = (const float*)d_in[4];
  char* ws = (char*)d_ws;
  u16* xb   = (u16*)(ws + (size_t)0);
  u16* Wqt  = (u16*)(ws + ((size_t)8  << 20));
  u16* Wkt  = (u16*)(ws + ((size_t)10 << 20));
  u16* Wvt  = (u16*)(ws + ((size_t)12 << 20));
  u16* Wot  = (u16*)(ws + ((size_t)14 << 20));
  u16* Qh   = (u16*)(ws + ((size_t)16 << 20));
  u16* Kh   = (u16*)(ws + ((size_t)24 << 20));
  u16* Vt   = (u16*)(ws + ((size_t)32 << 20));
  u16* ctxb = (u16*)(ws + ((size_t)40 << 20));

  prep_kernel<<<5120, 256, 0, stream>>>(x, wq, wk, wv, wo, xb, Wqt, Wkt, Wvt, Wot);
  qkv_gemm_kernel<<<dim3(32, 8, 3), 256, 0, stream>>>(xb, Wqt, Wkt, Wvt, Qh, Kh, Vt);
  attn_kernel<<<dim3(16, 32), 512, 0, stream>>>(Qh, Kh, Vt, ctxb);
  out_gemm_kernel<<<dim3(32, 8), 256, 0, stream>>>(ctxb, Wot, (float*)d_out);
}

// Round 6
// 135.460 us; speedup vs baseline: 1.0602x; 1.0602x over previous
//
#include <hip/hip_runtime.h>
#include <hip/hip_bf16.h>
#include <cstdint>

using u16 = unsigned short;
typedef short bf16x8 __attribute__((ext_vector_type(8)));
typedef float f32x4 __attribute__((ext_vector_type(4)));
typedef float f32x16 __attribute__((ext_vector_type(16)));
typedef u16 u16x4 __attribute__((ext_vector_type(4)));
typedef u16 u16x8 __attribute__((ext_vector_type(8)));

// ---------- helpers ----------
__device__ __forceinline__ u16 f2bf(float f) {
  union { float f; uint32_t u; } v; v.f = f;
  uint32_t r = (v.u + 0x7fffu + ((v.u >> 16) & 1u)) >> 16;  // RNE
  return (u16)r;
}

__device__ __forceinline__ float bf2f(u16 u) {
  union { uint32_t u; float f; } v; v.u = (uint32_t)u << 16; return v.f;
}

__device__ __forceinline__ void async16(const void* g, void* l) {
  __builtin_amdgcn_global_load_lds(
      (const __attribute__((address_space(1))) uint32_t*)g,
      (__attribute__((address_space(3))) uint32_t*)l, 16, 0, 0);
}

__device__ __forceinline__ uint32_t cvtpk(float a, float b) {
  uint32_t r;
  asm("v_cvt_pk_bf16_f32 %0, %1, %2" : "=v"(r) : "v"(a), "v"(b));
  return r;
}

// swap upper 32 lanes of a with lower 32 lanes of b
__device__ __forceinline__ void plswap(uint32_t& a, uint32_t& b) {
  asm volatile("v_permlane32_swap_b32 %0, %1" : "+v"(a), "+v"(b));
}

// ---------- fused prep: cvt x (blocks 0..4095) + 4x weight transpose (4096..5119) ----------
__global__ __launch_bounds__(256) void prep_kernel(
    const float* __restrict__ x, const float* __restrict__ wq, const float* __restrict__ wk,
    const float* __restrict__ wv, const float* __restrict__ wo,
    u16* __restrict__ xb, u16* __restrict__ Wqt, u16* __restrict__ Wkt,
    u16* __restrict__ Wvt, u16* __restrict__ Wot) {
  __shared__ float tile[64][65];
  const int tid = threadIdx.x;
  const int bid = blockIdx.x;
  if (bid < 4096) {
    int i = (bid * 256 + tid) * 4;
    float4 v = *(const float4*)(x + i);
    u16x4 o;
    o[0] = f2bf(v.x); o[1] = f2bf(v.y); o[2] = f2bf(v.z); o[3] = f2bf(v.w);
    *(u16x4*)(xb + i) = o;
    return;
  }
  const int id = bid - 4096;
  const int wsel = id >> 8, sub = id & 255;
  const float* W = (wsel == 0) ? wq : (wsel == 1) ? wk : (wsel == 2) ? wv : wo;
  u16* Wt = (wsel == 0) ? Wqt : (wsel == 1) ? Wkt : (wsel == 2) ? Wvt : Wot;
  const int k0 = (sub & 15) * 64, n0 = (sub >> 4) * 64;
#pragma unroll
  for (int i = 0; i < 4; ++i) {
    int c = i * 256 + tid;
    int r = c >> 4, c4 = c & 15;
    float4 v = *(const float4*)(W + (size_t)(k0 + r) * 1024 + n0 + c4 * 4);
    tile[r][c4 * 4 + 0] = v.x; tile[r][c4 * 4 + 1] = v.y;
    tile[r][c4 * 4 + 2] = v.z; tile[r][c4 * 4 + 3] = v.w;
  }
  __syncthreads();
#pragma unroll
  for (int i = 0; i < 2; ++i) {
    int c = i * 256 + tid;
    int n = c >> 3, kc = c & 7;
    u16x8 o;
#pragma unroll
    for (int j = 0; j < 8; ++j) o[j] = f2bf(tile[kc * 8 + j][n]);
    *(u16x8*)(Wt + (size_t)(n0 + n) * 1024 + k0 + kc * 8) = o;
  }
}

// ---------- shared GEMM mainloop: C(128x128) = A(128xK) * Bt(128xK)^T, K=1024 ----------
__device__ __forceinline__ void stage_ab(const u16* A, const u16* Bt, int m0, int n0, int kt,
                                         u16* As, u16* Bs, int w, int lane) {
#pragma unroll
  for (int c = 0; c < 2; ++c) {
    int chunk = w * 128 + c * 64 + lane;
    int row = chunk >> 2, cc = chunk & 3;
    int koff = kt * 32 + ((cc ^ (row & 3)) << 3);
    const u16* ga = A + (size_t)(m0 + row) * 1024 + koff;
    async16(ga, As + (size_t)(w * 128 + c * 64) * 8);
    const u16* gb = Bt + (size_t)(n0 + row) * 1024 + koff;
    async16(gb, Bs + (size_t)(w * 128 + c * 64) * 8);
  }
}

__device__ __forceinline__ void gemm_mainloop(const u16* A, const u16* Bt, int m0, int n0,
                                              u16 (*As)[4096], u16 (*Bs)[4096], f32x4 acc[4][4]) {
  const int tid = threadIdx.x, w = tid >> 6, lane = tid & 63, lo = lane & 15, hi = lane >> 4;
  const int mb = (w >> 1) * 64, nb = (w & 1) * 64;
  stage_ab(A, Bt, m0, n0, 0, As[0], Bs[0], w, lane);
  __syncthreads();
  for (int kt = 0; kt < 32; ++kt) {
    int cur = kt & 1;
    if (kt + 1 < 32) stage_ab(A, Bt, m0, n0, kt + 1, As[cur ^ 1], Bs[cur ^ 1], w, lane);
    bf16x8 af[4], bfr[4];
#pragma unroll
    for (int i = 0; i < 4; ++i) {
      int ra = mb + i * 16 + lo;
      af[i] = *(const bf16x8*)(As[cur] + ra * 32 + ((hi ^ (ra & 3)) << 3));
      int rb = nb + i * 16 + lo;
      bfr[i] = *(const bf16x8*)(Bs[cur] + rb * 32 + ((hi ^ (rb & 3)) << 3));
    }
#pragma unroll
    for (int i = 0; i < 4; ++i)
#pragma unroll
      for (int j = 0; j < 4; ++j)
        acc[i][j] = __builtin_amdgcn_mfma_f32_16x16x32_bf16(af[i], bfr[j], acc[i][j], 0, 0, 0);
    __syncthreads();
  }
}

// ---------- QKV projection + RoPE + scatter ----------
__global__ __launch_bounds__(256) void qkv_gemm_kernel(
    const u16* __restrict__ xb, const u16* __restrict__ Wqt, const u16* __restrict__ Wkt,
    const u16* __restrict__ Wvt, u16* __restrict__ Qh, u16* __restrict__ Kh, u16* __restrict__ Vt) {
  __shared__ u16 As[2][4096];
  __shared__ u16 Bs[2][4096];
  const int mode = blockIdx.z;
  const u16* Bt = (mode == 0) ? Wqt : (mode == 1) ? Wkt : Wvt;
  const int m0 = blockIdx.x * 128, n0 = blockIdx.y * 128;
  f32x4 acc[4][4];
  const f32x4 z4 = {0.f, 0.f, 0.f, 0.f};
#pragma unroll
  for (int i = 0; i < 4; ++i)
#pragma unroll
    for (int j = 0; j < 4; ++j) acc[i][j] = z4;
  gemm_mainloop(xb, Bt, m0, n0, As, Bs, acc);

  const int tid = threadIdx.x, w = tid >> 6, lane = tid & 63, lo = lane & 15, hi = lane >> 4;
  const int h = blockIdx.y * 2 + (w & 1);
  const int mrow0 = m0 + (w >> 1) * 64;
  if (mode < 2) {
    u16* Out = (mode == 0) ? Qh : Kh;
    // Q pre-scaled by 1/sqrt(64) * log2(e): attention scores land in exp2 domain
    const float qscale = (mode == 0) ? 0.18033688011112042f : 1.0f;
    const float invf0 = exp2f(-(float)lo * 0.41524101186092034f);
    const float invf1 = invf0 * 0.01f;
#pragma unroll
    for (int mi = 0; mi < 4; ++mi) {
#pragma unroll
      for (int r = 0; r < 4; ++r) {
        int tg = mrow0 + mi * 16 + hi * 4 + r;
        int b = tg >> 11, tp = tg & 2047;
        float c0, s0, c1, s1;
        __sincosf((float)tp * invf0, &s0, &c0);
        __sincosf((float)tp * invf1, &s1, &c1);
        size_t obase = ((size_t)(b * 16 + h) * 2048 + tp) * 64 + lo;
#pragma unroll
        for (int nf = 0; nf < 4; ++nf) {
          float v = acc[mi][nf][r];
          float rot = (nf < 2) ? -acc[mi][nf + 2][r] : acc[mi][nf - 2][r];
          float cs = (nf & 1) ? c1 : c0;
          float sn = (nf & 1) ? s1 : s0;
          Out[obase + nf * 16] = f2bf((v * cs + rot * sn) * qscale);
        }
      }
    }
  } else {
#pragma unroll
    for (int mi = 0; mi < 4; ++mi) {
      int tg0 = mrow0 + mi * 16 + hi * 4;
      int b = tg0 >> 11, tp0 = tg0 & 2047;
#pragma unroll
      for (int nf = 0; nf < 4; ++nf) {
        int d = nf * 16 + lo;
        u16x4 pk;
#pragma unroll
        for (int r = 0; r < 4; ++r) pk[r] = f2bf(acc[mi][nf][r]);
        *(u16x4*)(Vt + ((size_t)(b * 16 + h) * 64 + d) * 2048 + tp0) = pk;
      }
    }
  }
}

// ---------- flash attention: 4 waves (2 q-sub x 2 key-halves), counted-vmcnt pipeline ----------
// grid (bh=32, qi=32), one 64-row q-tile per block. qt = f(qi) balances the 4 blocks
// landing on each CU ({qi, qi+8, qi+16, qi+24} -> total 66 iters/CU) and keeps each
// bh on one XCD (L2-resident K/V). Loop uses raw s_barrier + s_waitcnt vmcnt(4):
// stage loads stay in flight a full iteration (T3/T4 minimum 2-phase, m218 pattern).
__global__ __launch_bounds__(256) void attn_kernel(const u16* __restrict__ Qh, const u16* __restrict__ Kh,
                                                   const u16* __restrict__ Vt, u16* __restrict__ ctx) {
  __shared__ u16 Ks[2][4096];      // [buf][key][8 chunks of 16B], chunk ^= key&7
  __shared__ u16 Vs[2][4096];      // [buf][d][8 chunks of 16B],   chunk ^= d&7
  __shared__ u16 Omb[2][32 * 68];  // bf16 merge buffer [sg][q*68 + d]
  __shared__ float Msm[2][32], Lsm[2][32];
  const int bh = blockIdx.x, qi = blockIdx.y;
  const int qt = (qi < 8) ? qi : (qi < 16) ? 23 - qi : (qi < 24) ? qi : 55 - qi;
  const int tid = threadIdx.x, w = tid >> 6, lane = tid & 63;
  const int sg = w >> 1, p = w & 1;    // sg: q-subgroup (32 rows), p: key half
  const int lo5 = lane & 31, hi = lane >> 5;
  const size_t kbh = (size_t)bh * 2048 * 64;
  const size_t vbh = (size_t)bh * 64 * 2048;
  const int bb = bh >> 4, h = bh & 15;
  const int q0 = qt * 64, nkv = qt + 1;
  const int tq = q0 + 32 * sg + lo5;

  // stage tile 0 into buf 0 (4 async16 per thread per stage)
#pragma unroll
  for (int c = 0; c < 2; ++c) {
    int chunk = c * 256 + tid;
    int row = chunk >> 3, cc = chunk & 7;
    int sw = (cc ^ (row & 7)) << 3;
    async16(Kh + kbh + (size_t)row * 64 + sw, Ks[0] + (size_t)chunk * 8);
    async16(Vt + vbh + (size_t)row * 2048 + sw, Vs[0] + (size_t)chunk * 8);
  }

  // Q fragments (B-operand): q = col = lo5, k-elems = 16*d + 8*hi + j
  const u16* Qrow = Qh + ((size_t)bh * 2048 + tq) * 64;
  bf16x8 qf[4];
#pragma unroll
  for (int d = 0; d < 4; ++d) qf[d] = *(const bf16x8*)(Qrow + 16 * d + 8 * hi);

  f32x16 O0, O1;
#pragma unroll
  for (int r = 0; r < 16; ++r) { O0[r] = 0.f; O1[r] = 0.f; }
  float m_run = -1e30f, l_run = 0.f;

  for (int t = 0; t < nkv; ++t) {
    const int cur = t & 1;
    if (t + 1 < nkv) {
      int kv0n = (t + 1) * 64;
#pragma unroll
      for (int c = 0; c < 2; ++c) {
        int chunk = c * 256 + tid;
        int row = chunk >> 3, cc = chunk & 7;
        int sw = (cc ^ (row & 7)) << 3;
        async16(Kh + kbh + (size_t)(kv0n + row) * 64 + sw, Ks[cur ^ 1] + (size_t)chunk * 8);
        async16(Vt + vbh + (size_t)row * 2048 + kv0n + sw, Vs[cur ^ 1] + (size_t)chunk * 8);
      }
      // wait for tile t's 4 loads (issued last iter); keep tile t+1's 4 in flight
      asm volatile("s_waitcnt vmcnt(4)" ::: "memory");
    } else {
      asm volatile("s_waitcnt vmcnt(0)" ::: "memory");
    }
    __builtin_amdgcn_s_barrier();  // buf[cur] fully staged (every wave waited its own)
    asm volatile("" ::: "memory");

    const u16* Ksc = Ks[cur];
    const u16* Vsc = Vs[cur];
    f32x16 s;
#pragma unroll
    for (int r = 0; r < 16; ++r) s[r] = 0.f;
    __builtin_amdgcn_s_setprio(1);
#pragma unroll
    for (int d = 0; d < 4; ++d) {
      int sw = ((2 * d + hi) ^ (lo5 & 7)) << 3;  // (32p+lo5)&7 == lo5&7
      bf16x8 ka = *(const bf16x8*)(Ksc + (32 * p + lo5) * 64 + sw);
      s = __builtin_amdgcn_mfma_f32_32x32x16_bf16(ka, qf[d], s, 0, 0, 0);
    }
    __builtin_amdgcn_s_setprio(0);

    // causal mask (diagonal tile only); lane's key r: (r&3)+8*(r>>2)+4*hi+32*p
    if (t == qt) {
      int ql = 32 * sg + lo5;
#pragma unroll
      for (int r = 0; r < 16; ++r) {
        int kl = (r & 3) + 8 * (r >> 2) + 4 * hi + 32 * p;
        if (kl > ql) s[r] = -1e30f;
      }
    }

    // in-register online softmax: lane owns q-row (16 keys; partner lane^32 has 16)
    float pm = -1e30f;
#pragma unroll
    for (int r = 0; r < 16; ++r) pm = fmaxf(pm, s[r]);
    pm = fmaxf(pm, __shfl_xor(pm, 32));
    float alpha = 1.f;
    if (!__all(pm <= m_run)) {
      float mnew = fmaxf(m_run, pm);
      alpha = exp2f(m_run - mnew);
      m_run = mnew;
#pragma unroll
      for (int r = 0; r < 16; ++r) { O0[r] *= alpha; O1[r] *= alpha; }
    }
    float ls = 0.f;
#pragma unroll
    for (int r = 0; r < 16; ++r) {
      float pr = exp2f(s[r] - m_run);
      s[r] = pr;
      ls += pr;
    }
    ls += __shfl_xor(ls, 32);
    l_run = l_run * alpha + ls;

    // pack P to bf16 words and build PV A-fragments via permlane swaps
    uint32_t W0[8];
#pragma unroll
    for (int i = 0; i < 8; ++i) W0[i] = cvtpk(s[2 * i], s[2 * i + 1]);

    __builtin_amdgcn_s_setprio(1);
#pragma unroll
    for (int ks = 0; ks < 2; ++ks) {
      uint32_t a = W0[4 * ks + 0], d2 = W0[4 * ks + 1], c2 = W0[4 * ks + 2], e2 = W0[4 * ks + 3];
      plswap(a, c2);
      plswap(d2, e2);
      union { uint32_t u[4]; bf16x8 v; } f;
      f.u[0] = a; f.u[1] = d2; f.u[2] = c2; f.u[3] = e2;
      int vch = 4 * p + 2 * ks + hi;                 // key chunk of this wave's half
      int sw = (vch ^ (lo5 & 7)) << 3;               // (32+lo5)&7 == lo5&7
      bf16x8 v0 = *(const bf16x8*)(Vsc + lo5 * 64 + sw);
      bf16x8 v1 = *(const bf16x8*)(Vsc + (32 + lo5) * 64 + sw);
      O0 = __builtin_amdgcn_mfma_f32_32x32x16_bf16(v0, f.v, O0, 0, 0, 0);
      O1 = __builtin_amdgcn_mfma_f32_32x32x16_bf16(v1, f.v, O1, 0, 0, 0);
    }
    __builtin_amdgcn_s_setprio(0);

    asm volatile("" ::: "memory");
    __builtin_amdgcn_s_barrier();  // compute(t) done before next stage overwrites buf[cur]
  }

  // ---- merge the two key-half partials (exact): p=1 publishes, p=0 combines ----
  if (p == 1) {
    u16* om = Omb[sg] + (size_t)lo5 * 68;
#pragma unroll
    for (int g = 0; g < 4; ++g) {
      int off = 8 * g + 4 * hi;
      u16x4 w0, w1;
#pragma unroll
      for (int j = 0; j < 4; ++j) { w0[j] = f2bf(O0[4 * g + j]); w1[j] = f2bf(O1[4 * g + j]); }
      *(u16x4*)(om + off) = w0;
      *(u16x4*)(om + 32 + off) = w1;
    }
    if (hi == 0) { Msm[sg][lo5] = m_run; Lsm[sg][lo5] = l_run; }
  }
  __syncthreads();
  if (p == 0) {
    float m1 = Msm[sg][lo5], l1 = Lsm[sg][lo5];
    float mm = fmaxf(m_run, m1);
    float a0 = exp2f(m_run - mm), a1 = exp2f(m1 - mm);
    float invl = 1.0f / (l_run * a0 + l1 * a1);
    const u16* om = Omb[sg] + (size_t)lo5 * 68;
    size_t rowb = ((size_t)(bb * 2048 + tq)) * 1024 + h * 64;
#pragma unroll
    for (int g = 0; g < 4; ++g) {
      int off = 8 * g + 4 * hi;
      u16x4 q1 = *(const u16x4*)(om + off);
      u16x4 pk;
#pragma unroll
      for (int j = 0; j < 4; ++j)
        pk[j] = f2bf((O0[4 * g + j] * a0 + bf2f(q1[j]) * a1) * invl);
      *(u16x4*)(ctx + rowb + off) = pk;
      u16x4 r1 = *(const u16x4*)(om + 32 + off);
#pragma unroll
      for (int j = 0; j < 4; ++j)
        pk[j] = f2bf((O1[4 * g + j] * a0 + bf2f(r1[j]) * a1) * invl);
      *(u16x4*)(ctx + rowb + 32 + off) = pk;
    }
  }
}

// ---------- output projection: out = ctx @ w_o (f32 out) ----------
__global__ __launch_bounds__(256) void out_gemm_kernel(const u16* __restrict__ ctxb,
                                                       const u16* __restrict__ Wot,
                                                       float* __restrict__ out) {
  __shared__ u16 As[2][4096];
  __shared__ u16 Bs[2][4096];
  const int m0 = blockIdx.x * 128, n0 = blockIdx.y * 128;
  f32x4 acc[4][4];
  const f32x4 z4 = {0.f, 0.f, 0.f, 0.f};
#pragma unroll
  for (int i = 0; i < 4; ++i)
#pragma unroll
    for (int j = 0; j < 4; ++j) acc[i][j] = z4;
  gemm_mainloop(ctxb, Wot, m0, n0, As, Bs, acc);
  const int tid = threadIdx.x, w = tid >> 6, lane = tid & 63, lo = lane & 15, hi = lane >> 4;
  const int col0 = n0 + (w & 1) * 64 + lo;
#pragma unroll
  for (int mi = 0; mi < 4; ++mi)
#pragma unroll
    for (int r = 0; r < 4; ++r) {
      int tg = m0 + (w >> 1) * 64 + mi * 16 + hi * 4 + r;
#pragma unroll
      for (int nf = 0; nf < 4; ++nf)
        out[(size_t)tg * 1024 + col0 + nf * 16] = acc[mi][nf][r];
    }
}

// ---------- launch ----------
extern "C" void kernel_launch(void* const* d_in, const int* in_sizes, int n_in,
                              void* d_out, int out_size, void* d_ws, size_t ws_size,
                              hipStream_t stream) {
  (void)in_sizes; (void)n_in; (void)out_size; (void)ws_size;
  const float* x  = (const float*)d_in[0];
  const float* wq = (const float*)d_in[1];
  const float* wk = (const float*)d_in[2];
  const float* wv = (const float*)d_in[3];
  const float* wo = (const float*)d_in[4];
  char* ws = (char*)d_ws;
  u16* xb   = (u16*)(ws + (size_t)0);
  u16* Wqt  = (u16*)(ws + ((size_t)8  << 20));
  u16* Wkt  = (u16*)(ws + ((size_t)10 << 20));
  u16* Wvt  = (u16*)(ws + ((size_t)12 << 20));
  u16* Wot  = (u16*)(ws + ((size_t)14 << 20));
  u16* Qh   = (u16*)(ws + ((size_t)16 << 20));
  u16* Kh   = (u16*)(ws + ((size_t)24 << 20));
  u16* Vt   = (u16*)(ws + ((size_t)32 << 20));
  u16* ctxb = (u16*)(ws + ((size_t)40 << 20));

  prep_kernel<<<5120, 256, 0, stream>>>(x, wq, wk, wv, wo, xb, Wqt, Wkt, Wvt, Wot);
  qkv_gemm_kernel<<<dim3(32, 8, 3), 256, 0, stream>>>(xb, Wqt, Wkt, Wvt, Qh, Kh, Vt);
  attn_kernel<<<dim3(32, 32), 256, 0, stream>>>(Qh, Kh, Vt, ctxb);
  out_gemm_kernel<<<dim3(32, 8), 256, 0, stream>>>(ctxb, Wot, (float*)d_out);
}

// Round 7
// 130.048 us; speedup vs baseline: 1.1043x; 1.0416x over previous
//
#include <hip/hip_runtime.h>
#include <hip/hip_bf16.h>
#include <cstdint>

using u16 = unsigned short;
typedef short bf16x8 __attribute__((ext_vector_type(8)));
typedef float f32x4 __attribute__((ext_vector_type(4)));
typedef float f32x16 __attribute__((ext_vector_type(16)));
typedef u16 u16x4 __attribute__((ext_vector_type(4)));
typedef u16 u16x8 __attribute__((ext_vector_type(8)));

// ---------- helpers ----------
__device__ __forceinline__ u16 f2bf(float f) {
  union { float f; uint32_t u; } v; v.f = f;
  uint32_t r = (v.u + 0x7fffu + ((v.u >> 16) & 1u)) >> 16;  // RNE
  return (u16)r;
}

__device__ __forceinline__ float bf2f(u16 u) {
  union { uint32_t u; float f; } v; v.u = (uint32_t)u << 16; return v.f;
}

__device__ __forceinline__ void async16(const void* g, void* l) {
  __builtin_amdgcn_global_load_lds(
      (const __attribute__((address_space(1))) uint32_t*)g,
      (__attribute__((address_space(3))) uint32_t*)l, 16, 0, 0);
}

__device__ __forceinline__ uint32_t cvtpk(float a, float b) {
  uint32_t r;
  asm("v_cvt_pk_bf16_f32 %0, %1, %2" : "=v"(r) : "v"(a), "v"(b));
  return r;
}

// swap upper 32 lanes of a with lower 32 lanes of b
__device__ __forceinline__ void plswap(uint32_t& a, uint32_t& b) {
  asm volatile("v_permlane32_swap_b32 %0, %1" : "+v"(a), "+v"(b));
}

// ---------- fused prep: cvt x (blocks 0..4095) + 4x weight transpose (4096..5119) ----------
__global__ __launch_bounds__(256) void prep_kernel(
    const float* __restrict__ x, const float* __restrict__ wq, const float* __restrict__ wk,
    const float* __restrict__ wv, const float* __restrict__ wo,
    u16* __restrict__ xb, u16* __restrict__ Wqt, u16* __restrict__ Wkt,
    u16* __restrict__ Wvt, u16* __restrict__ Wot) {
  __shared__ float tile[64][65];
  const int tid = threadIdx.x;
  const int bid = blockIdx.x;
  if (bid < 4096) {
    int i = (bid * 256 + tid) * 4;
    float4 v = *(const float4*)(x + i);
    u16x4 o;
    o[0] = f2bf(v.x); o[1] = f2bf(v.y); o[2] = f2bf(v.z); o[3] = f2bf(v.w);
    *(u16x4*)(xb + i) = o;
    return;
  }
  const int id = bid - 4096;
  const int wsel = id >> 8, sub = id & 255;
  const float* W = (wsel == 0) ? wq : (wsel == 1) ? wk : (wsel == 2) ? wv : wo;
  u16* Wt = (wsel == 0) ? Wqt : (wsel == 1) ? Wkt : (wsel == 2) ? Wvt : Wot;
  const int k0 = (sub & 15) * 64, n0 = (sub >> 4) * 64;
#pragma unroll
  for (int i = 0; i < 4; ++i) {
    int c = i * 256 + tid;
    int r = c >> 4, c4 = c & 15;
    float4 v = *(const float4*)(W + (size_t)(k0 + r) * 1024 + n0 + c4 * 4);
    tile[r][c4 * 4 + 0] = v.x; tile[r][c4 * 4 + 1] = v.y;
    tile[r][c4 * 4 + 2] = v.z; tile[r][c4 * 4 + 3] = v.w;
  }
  __syncthreads();
#pragma unroll
  for (int i = 0; i < 2; ++i) {
    int c = i * 256 + tid;
    int n = c >> 3, kc = c & 7;
    u16x8 o;
#pragma unroll
    for (int j = 0; j < 8; ++j) o[j] = f2bf(tile[kc * 8 + j][n]);
    *(u16x8*)(Wt + (size_t)(n0 + n) * 1024 + k0 + kc * 8) = o;
  }
}

// ---------- shared GEMM mainloop: C(128x128) = A(128xK) * Bt(128xK)^T, K=1024 ----------
__device__ __forceinline__ void stage_ab(const u16* A, const u16* Bt, int m0, int n0, int kt,
                                         u16* As, u16* Bs, int w, int lane) {
#pragma unroll
  for (int c = 0; c < 2; ++c) {
    int chunk = w * 128 + c * 64 + lane;
    int row = chunk >> 2, cc = chunk & 3;
    int koff = kt * 32 + ((cc ^ (row & 3)) << 3);
    const u16* ga = A + (size_t)(m0 + row) * 1024 + koff;
    async16(ga, As + (size_t)(w * 128 + c * 64) * 8);
    const u16* gb = Bt + (size_t)(n0 + row) * 1024 + koff;
    async16(gb, Bs + (size_t)(w * 128 + c * 64) * 8);
  }
}

__device__ __forceinline__ void gemm_mainloop(const u16* A, const u16* Bt, int m0, int n0,
                                              u16 (*As)[4096], u16 (*Bs)[4096], f32x4 acc[4][4]) {
  const int tid = threadIdx.x, w = tid >> 6, lane = tid & 63, lo = lane & 15, hi = lane >> 4;
  const int mb = (w >> 1) * 64, nb = (w & 1) * 64;
  stage_ab(A, Bt, m0, n0, 0, As[0], Bs[0], w, lane);
  __syncthreads();
  for (int kt = 0; kt < 32; ++kt) {
    int cur = kt & 1;
    if (kt + 1 < 32) stage_ab(A, Bt, m0, n0, kt + 1, As[cur ^ 1], Bs[cur ^ 1], w, lane);
    bf16x8 af[4], bfr[4];
#pragma unroll
    for (int i = 0; i < 4; ++i) {
      int ra = mb + i * 16 + lo;
      af[i] = *(const bf16x8*)(As[cur] + ra * 32 + ((hi ^ (ra & 3)) << 3));
      int rb = nb + i * 16 + lo;
      bfr[i] = *(const bf16x8*)(Bs[cur] + rb * 32 + ((hi ^ (rb & 3)) << 3));
    }
#pragma unroll
    for (int i = 0; i < 4; ++i)
#pragma unroll
      for (int j = 0; j < 4; ++j)
        acc[i][j] = __builtin_amdgcn_mfma_f32_16x16x32_bf16(af[i], bfr[j], acc[i][j], 0, 0, 0);
    __syncthreads();
  }
}

// ---------- QKV projection + RoPE + scatter ----------
__global__ __launch_bounds__(256) void qkv_gemm_kernel(
    const u16* __restrict__ xb, const u16* __restrict__ Wqt, const u16* __restrict__ Wkt,
    const u16* __restrict__ Wvt, u16* __restrict__ Qh, u16* __restrict__ Kh, u16* __restrict__ Vt) {
  __shared__ u16 As[2][4096];
  __shared__ u16 Bs[2][4096];
  const int mode = blockIdx.z;
  const u16* Bt = (mode == 0) ? Wqt : (mode == 1) ? Wkt : Wvt;
  const int m0 = blockIdx.x * 128, n0 = blockIdx.y * 128;
  f32x4 acc[4][4];
  const f32x4 z4 = {0.f, 0.f, 0.f, 0.f};
#pragma unroll
  for (int i = 0; i < 4; ++i)
#pragma unroll
    for (int j = 0; j < 4; ++j) acc[i][j] = z4;
  gemm_mainloop(xb, Bt, m0, n0, As, Bs, acc);

  const int tid = threadIdx.x, w = tid >> 6, lane = tid & 63, lo = lane & 15, hi = lane >> 4;
  const int h = blockIdx.y * 2 + (w & 1);
  const int mrow0 = m0 + (w >> 1) * 64;
  if (mode < 2) {
    u16* Out = (mode == 0) ? Qh : Kh;
    // Q pre-scaled by 1/sqrt(64) * log2(e): attention scores land in exp2 domain
    const float qscale = (mode == 0) ? 0.18033688011112042f : 1.0f;
    const float invf0 = exp2f(-(float)lo * 0.41524101186092034f);
    const float invf1 = invf0 * 0.01f;
#pragma unroll
    for (int mi = 0; mi < 4; ++mi) {
#pragma unroll
      for (int r = 0; r < 4; ++r) {
        int tg = mrow0 + mi * 16 + hi * 4 + r;
        int b = tg >> 11, tp = tg & 2047;
        float c0, s0, c1, s1;
        __sincosf((float)tp * invf0, &s0, &c0);
        __sincosf((float)tp * invf1, &s1, &c1);
        size_t obase = ((size_t)(b * 16 + h) * 2048 + tp) * 64 + lo;
#pragma unroll
        for (int nf = 0; nf < 4; ++nf) {
          float v = acc[mi][nf][r];
          float rot = (nf < 2) ? -acc[mi][nf + 2][r] : acc[mi][nf - 2][r];
          float cs = (nf & 1) ? c1 : c0;
          float sn = (nf & 1) ? s1 : s0;
          Out[obase + nf * 16] = f2bf((v * cs + rot * sn) * qscale);
        }
      }
    }
  } else {
#pragma unroll
    for (int mi = 0; mi < 4; ++mi) {
      int tg0 = mrow0 + mi * 16 + hi * 4;
      int b = tg0 >> 11, tp0 = tg0 & 2047;
#pragma unroll
      for (int nf = 0; nf < 4; ++nf) {
        int d = nf * 16 + lo;
        u16x4 pk;
#pragma unroll
        for (int r = 0; r < 4; ++r) pk[r] = f2bf(acc[mi][nf][r]);
        *(u16x4*)(Vt + ((size_t)(b * 16 + h) * 64 + d) * 2048 + tp0) = pk;
      }
    }
  }
}

// ---------- flash attention: 4 waves (2 q-sub x 2 key-halves), counted-vmcnt pipeline ----------
// grid (bh=32, qi=32). qt=f(qi) equalizes per-CU totals (66 iters) and keeps each bh
// on one XCD (L2-resident K/V, verified r6: FETCH 92->12MB). LDS = 33.3KB so FOUR
// blocks are co-resident per CU from t=0 (16 waves/CU): the merge buffer is aliased
// into Ks (dead after the KV loop drains vmcnt(0) + trailing barrier).
__global__ __launch_bounds__(256) void attn_kernel(const u16* __restrict__ Qh, const u16* __restrict__ Kh,
                                                   const u16* __restrict__ Vt, u16* __restrict__ ctx) {
  __shared__ u16 Ks[2][4096];      // [buf][key][8 chunks of 16B], chunk ^= key&7 ; aliased as merge buf after loop
  __shared__ u16 Vs[2][4096];      // [buf][d][8 chunks of 16B],   chunk ^= d&7
  __shared__ float Msm[2][32], Lsm[2][32];
  const int bh = blockIdx.x, qi = blockIdx.y;
  const int qt = (qi < 8) ? qi : (qi < 16) ? 23 - qi : (qi < 24) ? qi : 55 - qi;
  const int tid = threadIdx.x, w = tid >> 6, lane = tid & 63;
  const int sg = w >> 1, p = w & 1;    // sg: q-subgroup (32 rows), p: key half
  const int lo5 = lane & 31, hi = lane >> 5;
  const size_t kbh = (size_t)bh * 2048 * 64;
  const size_t vbh = (size_t)bh * 64 * 2048;
  const int bb = bh >> 4, h = bh & 15;
  const int q0 = qt * 64, nkv = qt + 1;
  const int tq = q0 + 32 * sg + lo5;

  // stage tile 0 into buf 0 (4 async16 per thread per stage)
#pragma unroll
  for (int c = 0; c < 2; ++c) {
    int chunk = c * 256 + tid;
    int row = chunk >> 3, cc = chunk & 7;
    int sw = (cc ^ (row & 7)) << 3;
    async16(Kh + kbh + (size_t)row * 64 + sw, Ks[0] + (size_t)chunk * 8);
    async16(Vt + vbh + (size_t)row * 2048 + sw, Vs[0] + (size_t)chunk * 8);
  }

  // Q fragments (B-operand): q = col = lo5, k-elems = 16*d + 8*hi + j
  const u16* Qrow = Qh + ((size_t)bh * 2048 + tq) * 64;
  bf16x8 qf[4];
#pragma unroll
  for (int d = 0; d < 4; ++d) qf[d] = *(const bf16x8*)(Qrow + 16 * d + 8 * hi);

  f32x16 O0, O1;
#pragma unroll
  for (int r = 0; r < 16; ++r) { O0[r] = 0.f; O1[r] = 0.f; }
  float m_run = -1e30f, l_run = 0.f;

  for (int t = 0; t < nkv; ++t) {
    const int cur = t & 1;
    if (t + 1 < nkv) {
      int kv0n = (t + 1) * 64;
#pragma unroll
      for (int c = 0; c < 2; ++c) {
        int chunk = c * 256 + tid;
        int row = chunk >> 3, cc = chunk & 7;
        int sw = (cc ^ (row & 7)) << 3;
        async16(Kh + kbh + (size_t)(kv0n + row) * 64 + sw, Ks[cur ^ 1] + (size_t)chunk * 8);
        async16(Vt + vbh + (size_t)row * 2048 + kv0n + sw, Vs[cur ^ 1] + (size_t)chunk * 8);
      }
      // wait for tile t's 4 loads (issued last iter); keep tile t+1's 4 in flight
      asm volatile("s_waitcnt vmcnt(4)" ::: "memory");
    } else {
      asm volatile("s_waitcnt vmcnt(0)" ::: "memory");
    }
    __builtin_amdgcn_s_barrier();  // buf[cur] fully staged (every wave waited its own)
    asm volatile("" ::: "memory");

    const u16* Ksc = Ks[cur];
    const u16* Vsc = Vs[cur];
    f32x16 s;
#pragma unroll
    for (int r = 0; r < 16; ++r) s[r] = 0.f;
    __builtin_amdgcn_s_setprio(1);
#pragma unroll
    for (int d = 0; d < 4; ++d) {
      int sw = ((2 * d + hi) ^ (lo5 & 7)) << 3;  // (32p+lo5)&7 == lo5&7
      bf16x8 ka = *(const bf16x8*)(Ksc + (32 * p + lo5) * 64 + sw);
      s = __builtin_amdgcn_mfma_f32_32x32x16_bf16(ka, qf[d], s, 0, 0, 0);
    }
    __builtin_amdgcn_s_setprio(0);

    // causal mask (diagonal tile only); lane's key r: (r&3)+8*(r>>2)+4*hi+32*p
    if (t == qt) {
      int ql = 32 * sg + lo5;
#pragma unroll
      for (int r = 0; r < 16; ++r) {
        int kl = (r & 3) + 8 * (r >> 2) + 4 * hi + 32 * p;
        if (kl > ql) s[r] = -1e30f;
      }
    }

    // in-register online softmax: lane owns q-row (16 keys; partner lane^32 has 16).
    // T13 defer: skip the O-rescale unless max grew by >11.5 (exp2-domain ~ e^8);
    // P then bounded by 2^11.5, safe in bf16/f32. Fully-masked waves keep m=-1e30
    // and are zero-weighted at merge (exp2(-1e30 - m_other) = 0) -- exact.
    float pm = -1e30f;
#pragma unroll
    for (int r = 0; r < 16; ++r) pm = fmaxf(pm, s[r]);
    pm = fmaxf(pm, __shfl_xor(pm, 32));
    float alpha = 1.f;
    if (!__all(pm <= m_run + 11.5f)) {
      float mnew = fmaxf(m_run, pm);
      alpha = exp2f(m_run - mnew);
      m_run = mnew;
#pragma unroll
      for (int r = 0; r < 16; ++r) { O0[r] *= alpha; O1[r] *= alpha; }
    }
    float ls = 0.f;
#pragma unroll
    for (int r = 0; r < 16; ++r) {
      float pr = exp2f(s[r] - m_run);
      s[r] = pr;
      ls += pr;
    }
    ls += __shfl_xor(ls, 32);
    l_run = l_run * alpha + ls;

    // pack P to bf16 words and build PV A-fragments via permlane swaps
    uint32_t W0[8];
#pragma unroll
    for (int i = 0; i < 8; ++i) W0[i] = cvtpk(s[2 * i], s[2 * i + 1]);

    __builtin_amdgcn_s_setprio(1);
#pragma unroll
    for (int ks = 0; ks < 2; ++ks) {
      uint32_t a = W0[4 * ks + 0], d2 = W0[4 * ks + 1], c2 = W0[4 * ks + 2], e2 = W0[4 * ks + 3];
      plswap(a, c2);
      plswap(d2, e2);
      union { uint32_t u[4]; bf16x8 v; } f;
      f.u[0] = a; f.u[1] = d2; f.u[2] = c2; f.u[3] = e2;
      int vch = 4 * p + 2 * ks + hi;                 // key chunk of this wave's half
      int sw = (vch ^ (lo5 & 7)) << 3;               // (32+lo5)&7 == lo5&7
      bf16x8 v0 = *(const bf16x8*)(Vsc + lo5 * 64 + sw);
      bf16x8 v1 = *(const bf16x8*)(Vsc + (32 + lo5) * 64 + sw);
      O0 = __builtin_amdgcn_mfma_f32_32x32x16_bf16(v0, f.v, O0, 0, 0, 0);
      O1 = __builtin_amdgcn_mfma_f32_32x32x16_bf16(v1, f.v, O1, 0, 0, 0);
    }
    __builtin_amdgcn_s_setprio(0);

    asm volatile("" ::: "memory");
    __builtin_amdgcn_s_barrier();  // compute(t) done before next stage overwrites buf[cur]
  }

  // ---- merge the two key-half partials (exact): p=1 publishes, p=0 combines ----
  // Merge buffer aliased into Ks (dead: vmcnt(0) drained + trailing barrier passed).
  u16* Omb = (u16*)Ks;
  if (p == 1) {
    u16* om = Omb + (size_t)(sg * 32 + lo5) * 68;
#pragma unroll
    for (int g = 0; g < 4; ++g) {
      int off = 8 * g + 4 * hi;
      u16x4 w0, w1;
#pragma unroll
      for (int j = 0; j < 4; ++j) { w0[j] = f2bf(O0[4 * g + j]); w1[j] = f2bf(O1[4 * g + j]); }
      *(u16x4*)(om + off) = w0;
      *(u16x4*)(om + 32 + off) = w1;
    }
    if (hi == 0) { Msm[sg][lo5] = m_run; Lsm[sg][lo5] = l_run; }
  }
  __syncthreads();
  if (p == 0) {
    float m1 = Msm[sg][lo5], l1 = Lsm[sg][lo5];
    float mm = fmaxf(m_run, m1);
    float a0 = exp2f(m_run - mm), a1 = exp2f(m1 - mm);
    float invl = 1.0f / (l_run * a0 + l1 * a1);
    const u16* om = Omb + (size_t)(sg * 32 + lo5) * 68;
    size_t rowb = ((size_t)(bb * 2048 + tq)) * 1024 + h * 64;
#pragma unroll
    for (int g = 0; g < 4; ++g) {
      int off = 8 * g + 4 * hi;
      u16x4 q1 = *(const u16x4*)(om + off);
      u16x4 pk;
#pragma unroll
      for (int j = 0; j < 4; ++j)
        pk[j] = f2bf((O0[4 * g + j] * a0 + bf2f(q1[j]) * a1) * invl);
      *(u16x4*)(ctx + rowb + off) = pk;
      u16x4 r1 = *(const u16x4*)(om + 32 + off);
#pragma unroll
      for (int j = 0; j < 4; ++j)
        pk[j] = f2bf((O1[4 * g + j] * a0 + bf2f(r1[j]) * a1) * invl);
      *(u16x4*)(ctx + rowb + 32 + off) = pk;
    }
  }
}

// ---------- output projection: out = ctx @ w_o (f32 out) ----------
__global__ __launch_bounds__(256) void out_gemm_kernel(const u16* __restrict__ ctxb,
                                                       const u16* __restrict__ Wot,
                                                       float* __restrict__ out) {
  __shared__ u16 As[2][4096];
  __shared__ u16 Bs[2][4096];
  const int m0 = blockIdx.x * 128, n0 = blockIdx.y * 128;
  f32x4 acc[4][4];
  const f32x4 z4 = {0.f, 0.f, 0.f, 0.f};
#pragma unroll
  for (int i = 0; i < 4; ++i)
#pragma unroll
    for (int j = 0; j < 4; ++j) acc[i][j] = z4;
  gemm_mainloop(ctxb, Wot, m0, n0, As, Bs, acc);
  const int tid = threadIdx.x, w = tid >> 6, lane = tid & 63, lo = lane & 15, hi = lane >> 4;
  const int col0 = n0 + (w & 1) * 64 + lo;
#pragma unroll
  for (int mi = 0; mi < 4; ++mi)
#pragma unroll
    for (int r = 0; r < 4; ++r) {
      int tg = m0 + (w >> 1) * 64 + mi * 16 + hi * 4 + r;
#pragma unroll
      for (int nf = 0; nf < 4; ++nf)
        out[(size_t)tg * 1024 + col0 + nf * 16] = acc[mi][nf][r];
    }
}

// ---------- launch ----------
extern "C" void kernel_launch(void* const* d_in, const int* in_sizes, int n_in,
                              void* d_out, int out_size, void* d_ws, size_t ws_size,
                              hipStream_t stream) {
  (void)in_sizes; (void)n_in; (void)out_size; (void)ws_size;
  const float* x  = (const float*)d_in[0];
  const float* wq = (const float*)d_in[1];
  const float* wk = (const float*)d_in[2];
  const float* wv = (const float*)d_in[3];
  const float* wo = (const float*)d_in[4];
  char* ws = (char*)d_ws;
  u16* xb   = (u16*)(ws + (size_t)0);
  u16* Wqt  = (u16*)(ws + ((size_t)8  << 20));
  u16* Wkt  = (u16*)(ws + ((size_t)10 << 20));
  u16* Wvt  = (u16*)(ws + ((size_t)12 << 20));
  u16* Wot  = (u16*)(ws + ((size_t)14 << 20));
  u16* Qh   = (u16*)(ws + ((size_t)16 << 20));
  u16* Kh   = (u16*)(ws + ((size_t)24 << 20));
  u16* Vt   = (u16*)(ws + ((size_t)32 << 20));
  u16* ctxb = (u16*)(ws + ((size_t)40 << 20));

  prep_kernel<<<5120, 256, 0, stream>>>(x, wq, wk, wv, wo, xb, Wqt, Wkt, Wvt, Wot);
  qkv_gemm_kernel<<<dim3(32, 8, 3), 256, 0, stream>>>(xb, Wqt, Wkt, Wvt, Qh, Kh, Vt);
  attn_kernel<<<dim3(32, 32), 256, 0, stream>>>(Qh, Kh, Vt, ctxb);
  out_gemm_kernel<<<dim3(32, 8), 256, 0, stream>>>(ctxb, Wot, (float*)d_out);
}